// Round 4
// baseline (783.202 us; speedup 1.0000x reference)
//
#include <hip/hip_runtime.h>
#include <math.h>

// Problem constants (fixed by setup_inputs): bs=128, seq=4096, hidden=128, fp32.
#define B_ 128
#define S_ 4096
#define H_ 128
#define SPLITS_ 16                // seq splits per batch -> 2048 blocks
#define CHUNK_ (S_ / SPLITS_)     // 256 positions per block
#define NPART_ (H_ + 2)           // per-partial: {m, l, ctx[128]}
#define PART_OFF_ 1024            // floats; counters live in ws[0..127]

// clang native vector type — __builtin_nontemporal_load requires a vector of
// scalar types, not HIP's struct-based float4.
typedef float f4v __attribute__((ext_vector_type(4)));

// Single fused kernel: streamed scores + online-softmax context partials,
// then the LAST block of each batch (per-batch atomic counter) merges the 16
// split partials, writes context, and normalizes the batch's 4096 raw scores
// in place (flash-style decode with split-K reduction fused via device-scope
// atomics + fences; per guide G16 the fence/atomic pair handles cross-XCD
// visibility).
__global__ __launch_bounds__(256) void s2s_attn_fused(
    const float* __restrict__ dec, const float* __restrict__ enc,
    float* __restrict__ attn, float* __restrict__ ctx_out,
    float* __restrict__ part_out, int* __restrict__ counters) {
  const int blk = blockIdx.x;
  const int b = blk / SPLITS_;
  const int split = blk - b * SPLITS_;
  const int t = threadIdx.x;
  const int w = t >> 6;        // wave 0..3
  const int lane = t & 63;
  const int half = lane >> 5;  // even/odd position owner
  const int l32 = lane & 31;   // h-slice owner: h = l32*4 .. +3

  __shared__ float s_score[CHUNK_];   // 1 KiB raw scores for coalesced write-out
  __shared__ float s_m[4];
  __shared__ float s_l[4];
  __shared__ float s_ctx[4][H_];      // 2 KiB per-wave context partials
  __shared__ int s_last;

  const f4v dv = *reinterpret_cast<const f4v*>(dec + b * H_ + l32 * 4);
  const float* encb = enc + (size_t)b * S_ * H_ + (size_t)split * CHUNK_ * H_;

  float m = -INFINITY, l = 0.f;
  float cx = 0.f, cy = 0.f, cz = 0.f, cw = 0.f;

#pragma unroll
  for (int i = 0; i < CHUNK_ / 32; ++i) {     // 8 iterations
    const int base = i * 32 + w * 8;          // this wave's 8 positions
    // 4 independent 1-KiB wave loads (nontemporal: enc is stream-once, keep
    // it out of L2 so scores/partials stay resident for the finisher)
    const f4v e0 = __builtin_nontemporal_load(
        reinterpret_cast<const f4v*>(encb + (size_t)(base + 0 + half) * H_ + l32 * 4));
    const f4v e1 = __builtin_nontemporal_load(
        reinterpret_cast<const f4v*>(encb + (size_t)(base + 2 + half) * H_ + l32 * 4));
    const f4v e2 = __builtin_nontemporal_load(
        reinterpret_cast<const f4v*>(encb + (size_t)(base + 4 + half) * H_ + l32 * 4));
    const f4v e3 = __builtin_nontemporal_load(
        reinterpret_cast<const f4v*>(encb + (size_t)(base + 6 + half) * H_ + l32 * 4));

    float p0 = e0.x * dv.x + e0.y * dv.y + e0.z * dv.z + e0.w * dv.w;
    float p1 = e1.x * dv.x + e1.y * dv.y + e1.z * dv.z + e1.w * dv.w;
    float p2 = e2.x * dv.x + e2.y * dv.y + e2.z * dv.z + e2.w * dv.w;
    float p3 = e3.x * dv.x + e3.y * dv.y + e3.z * dv.z + e3.w * dv.w;
#pragma unroll
    for (int s = 1; s <= 16; s <<= 1) {   // 20 independent shfls, DS-pipelined
      p0 += __shfl_xor(p0, s);
      p1 += __shfl_xor(p1, s);
      p2 += __shfl_xor(p2, s);
      p3 += __shfl_xor(p3, s);
    }
    if (l32 == 0) {
      s_score[base + 0 + half] = p0;
      s_score[base + 2 + half] = p1;
      s_score[base + 4 + half] = p2;
      s_score[base + 6 + half] = p3;
    }
    // batched online-softmax update: one rescale per 4 positions
    const float mb = fmaxf(fmaxf(p0, p1), fmaxf(p2, p3));
    const float mn = fmaxf(m, mb);
    const float corr = __expf(m - mn);   // first iter: exp(-inf)=0, exact
    const float w0 = __expf(p0 - mn);
    const float w1 = __expf(p1 - mn);
    const float w2 = __expf(p2 - mn);
    const float w3 = __expf(p3 - mn);
    l = l * corr + (w0 + w1 + w2 + w3);
    cx = cx * corr + w0 * e0.x + w1 * e1.x + w2 * e2.x + w3 * e3.x;
    cy = cy * corr + w0 * e0.y + w1 * e1.y + w2 * e2.y + w3 * e3.y;
    cz = cz * corr + w0 * e0.z + w1 * e1.z + w2 * e2.z + w3 * e3.z;
    cw = cw * corr + w0 * e0.w + w1 * e1.w + w2 * e2.w + w3 * e3.w;
    m = mn;
  }

  // merge the two 32-lane halves of the wave
  const float m_o = __shfl_xor(m, 32);
  const float l_o = __shfl_xor(l, 32);
  const float cx_o = __shfl_xor(cx, 32);
  const float cy_o = __shfl_xor(cy, 32);
  const float cz_o = __shfl_xor(cz, 32);
  const float cw_o = __shfl_xor(cw, 32);
  const float M = fmaxf(m, m_o);
  const float ea = __expf(m - M);
  const float eb = __expf(m_o - M);
  if (lane == 0) { s_m[w] = M; s_l[w] = l * ea + l_o * eb; }
  if (half == 0) {
    s_ctx[w][l32 * 4 + 0] = cx * ea + cx_o * eb;
    s_ctx[w][l32 * 4 + 1] = cy * ea + cy_o * eb;
    s_ctx[w][l32 * 4 + 2] = cz * ea + cz_o * eb;
    s_ctx[w][l32 * 4 + 3] = cw * ea + cw_o * eb;
  }
  __syncthreads();

  // merge the block's 4 waves, emit one partial {m,l,ctx[128]} per block
  float* part = part_out + (size_t)blk * NPART_;
  if (t < H_) {
    const float m0 = s_m[0], m1 = s_m[1], m2 = s_m[2], m3 = s_m[3];
    const float Mb = fmaxf(fmaxf(m0, m1), fmaxf(m2, m3));
    const float e0 = __expf(m0 - Mb), e1 = __expf(m1 - Mb);
    const float e2 = __expf(m2 - Mb), e3 = __expf(m3 - Mb);
    if (t == 0) {
      part[0] = Mb;
      part[1] = s_l[0] * e0 + s_l[1] * e1 + s_l[2] * e2 + s_l[3] * e3;
    }
    part[2 + t] = s_ctx[0][t] * e0 + s_ctx[1][t] * e1 +
                  s_ctx[2][t] * e2 + s_ctx[3][t] * e3;
  }

  // coalesced raw-score write-out for this block's 256 positions
  float* so = attn + (size_t)b * S_ + (size_t)split * CHUNK_;
  if (t < CHUNK_) so[t] = s_score[t];

  // ---- split-K completion protocol: last block of batch b finishes it ----
  __threadfence();                 // make this thread's global writes visible
  __syncthreads();                 // all threads' writes done + fenced
  if (t == 0) {
    const int old = atomicAdd(&counters[b], 1);  // device-scope by default
    s_last = (old == SPLITS_ - 1) ? 1 : 0;
  }
  __syncthreads();
  if (!s_last) return;
  __threadfence();                 // acquire: see other blocks' writes

  // ---- finisher: merge 16 partials, write context, normalize scores ----
  const float* pb = part_out + (size_t)b * SPLITS_ * NPART_;
  float mv[SPLITS_], lv[SPLITS_], ex[SPLITS_];
  float Mg = -INFINITY;
#pragma unroll
  for (int p = 0; p < SPLITS_; ++p) {
    mv[p] = pb[p * NPART_];
    lv[p] = pb[p * NPART_ + 1];
    Mg = fmaxf(Mg, mv[p]);
  }
  float L = 0.f;
#pragma unroll
  for (int p = 0; p < SPLITS_; ++p) {
    ex[p] = __expf(mv[p] - Mg);
    L += lv[p] * ex[p];
  }
  const float invL = 1.0f / L;

  if (t < H_) {
    float c = 0.f;
#pragma unroll
    for (int p = 0; p < SPLITS_; ++p) c += pb[p * NPART_ + 2 + t] * ex[p];
    ctx_out[(size_t)b * H_ + t] = c * invL;
  }

  f4v* ab = reinterpret_cast<f4v*>(attn + (size_t)b * S_);
#pragma unroll
  for (int j = t; j < S_ / 4; j += 256) {
    f4v v = ab[j];
    v.x = __expf(v.x - Mg) * invL;
    v.y = __expf(v.y - Mg) * invL;
    v.z = __expf(v.z - Mg) * invL;
    v.w = __expf(v.w - Mg) * invL;
    ab[j] = v;
  }
}

extern "C" void kernel_launch(void* const* d_in, const int* in_sizes, int n_in,
                              void* d_out, int out_size, void* d_ws, size_t ws_size,
                              hipStream_t stream) {
  const float* dec = (const float*)d_in[0];   // (128,128) fp32
  const float* enc = (const float*)d_in[1];   // (128,4096,128) fp32
  float* out = (float*)d_out;
  float* attn = out;                          // (128,4096) — scores, then probs
  float* ctx = out + (size_t)B_ * S_;         // (128,128)
  int* counters = (int*)d_ws;                 // 128 ints (ws is 0xAA-poisoned)
  float* part = (float*)d_ws + PART_OFF_;     // 2048 * 130 floats

  (void)hipMemsetAsync(counters, 0, B_ * sizeof(int), stream);  // graph-capturable
  s2s_attn_fused<<<dim3(B_ * SPLITS_), dim3(256), 0, stream>>>(
      dec, enc, attn, ctx, part, counters);
}

// Round 5
// 360.923 us; speedup vs baseline: 2.1700x; 2.1700x over previous
//
#include <hip/hip_runtime.h>
#include <math.h>

// Problem constants (fixed by setup_inputs): bs=128, seq=4096, hidden=128, fp32.
#define B_ 128
#define S_ 4096
#define H_ 128
#define SPLITS_ 16                // seq splits per batch -> 2048 blocks in pass1
#define CHUNK_ (S_ / SPLITS_)     // 256 positions per block
#define NPART_ (H_ + 2)           // per-partial: {m, l, ctx[128]}

// ---------------- Pass 1: streamed scores + online-softmax context partials ----
// Block = (batch b, split). 256 threads = 4 waves. Each wave-iteration issues
// FOUR independent 1-KiB loads (8 positions): lane half 0 owns even positions,
// half 1 odd; lane l32 owns h = l32*4..+3. Score reduced inside each 32-lane
// half via 5 independent-per-position __shfl_xor chains; online-softmax
// rescale batched (once per 4 positions per half). Raw scores go to the attn
// output region; pass 2 normalizes in place.
// NOTE (R4 post-mortem): do NOT fuse the split-K reduction via device-scope
// atomics+fences — __threadfence() on multi-XCD CDNA4 = L2 writeback/inv per
// block, which took the kernel from ~50us to 540us. The kernel boundary is
// the cheap cross-block barrier.
__global__ __launch_bounds__(256) void s2s_attn_pass1(
    const float* __restrict__ dec, const float* __restrict__ enc,
    float* __restrict__ score_out, float* __restrict__ part_out) {
  const int blk = blockIdx.x;
  const int b = blk / SPLITS_;
  const int split = blk - b * SPLITS_;
  const int t = threadIdx.x;
  const int w = t >> 6;        // wave 0..3
  const int lane = t & 63;
  const int half = lane >> 5;  // even/odd position owner
  const int l32 = lane & 31;   // h-slice owner: h = l32*4 .. +3

  __shared__ float s_score[CHUNK_];   // 1 KiB raw scores for coalesced write-out
  __shared__ float s_m[4];
  __shared__ float s_l[4];
  __shared__ float s_ctx[4][H_];      // 2 KiB per-wave context partials

  const float4 dv = *reinterpret_cast<const float4*>(dec + b * H_ + l32 * 4);
  const float* encb = enc + (size_t)b * S_ * H_ + (size_t)split * CHUNK_ * H_;

  float m = -INFINITY, l = 0.f;
  float cx = 0.f, cy = 0.f, cz = 0.f, cw = 0.f;

#pragma unroll
  for (int i = 0; i < CHUNK_ / 32; ++i) {     // 8 iterations
    const int base = i * 32 + w * 8;          // this wave's 8 positions
    // 4 independent 1-KiB wave loads; this lane's positions: base + j*2 + half
    const float4 e0 = *reinterpret_cast<const float4*>(
        encb + (size_t)(base + 0 + half) * H_ + l32 * 4);
    const float4 e1 = *reinterpret_cast<const float4*>(
        encb + (size_t)(base + 2 + half) * H_ + l32 * 4);
    const float4 e2 = *reinterpret_cast<const float4*>(
        encb + (size_t)(base + 4 + half) * H_ + l32 * 4);
    const float4 e3 = *reinterpret_cast<const float4*>(
        encb + (size_t)(base + 6 + half) * H_ + l32 * 4);

    float p0 = e0.x * dv.x + e0.y * dv.y + e0.z * dv.z + e0.w * dv.w;
    float p1 = e1.x * dv.x + e1.y * dv.y + e1.z * dv.z + e1.w * dv.w;
    float p2 = e2.x * dv.x + e2.y * dv.y + e2.z * dv.z + e2.w * dv.w;
    float p3 = e3.x * dv.x + e3.y * dv.y + e3.z * dv.z + e3.w * dv.w;
    // 20 independent shfls — pipelined through the DS unit
#pragma unroll
    for (int s = 1; s <= 16; s <<= 1) {
      p0 += __shfl_xor(p0, s);
      p1 += __shfl_xor(p1, s);
      p2 += __shfl_xor(p2, s);
      p3 += __shfl_xor(p3, s);
    }
    if (l32 == 0) {
      s_score[base + 0 + half] = p0;
      s_score[base + 2 + half] = p1;
      s_score[base + 4 + half] = p2;
      s_score[base + 6 + half] = p3;
    }
    // batched online-softmax update: one rescale per 4 positions
    const float mb = fmaxf(fmaxf(p0, p1), fmaxf(p2, p3));
    const float mn = fmaxf(m, mb);
    const float corr = __expf(m - mn);   // first iter: exp(-inf)=0, exact
    const float w0 = __expf(p0 - mn);
    const float w1 = __expf(p1 - mn);
    const float w2 = __expf(p2 - mn);
    const float w3 = __expf(p3 - mn);
    l = l * corr + (w0 + w1 + w2 + w3);
    cx = cx * corr + w0 * e0.x + w1 * e1.x + w2 * e2.x + w3 * e3.x;
    cy = cy * corr + w0 * e0.y + w1 * e1.y + w2 * e2.y + w3 * e3.y;
    cz = cz * corr + w0 * e0.z + w1 * e1.z + w2 * e2.z + w3 * e3.z;
    cw = cw * corr + w0 * e0.w + w1 * e1.w + w2 * e2.w + w3 * e3.w;
    m = mn;
  }

  // merge the two 32-lane halves of the wave (both halves hold full h-slices)
  const float m_o = __shfl_xor(m, 32);
  const float l_o = __shfl_xor(l, 32);
  const float cx_o = __shfl_xor(cx, 32);
  const float cy_o = __shfl_xor(cy, 32);
  const float cz_o = __shfl_xor(cz, 32);
  const float cw_o = __shfl_xor(cw, 32);
  const float M = fmaxf(m, m_o);
  const float ea = __expf(m - M);
  const float eb = __expf(m_o - M);
  if (lane == 0) { s_m[w] = M; s_l[w] = l * ea + l_o * eb; }
  if (half == 0) {
    s_ctx[w][l32 * 4 + 0] = cx * ea + cx_o * eb;
    s_ctx[w][l32 * 4 + 1] = cy * ea + cy_o * eb;
    s_ctx[w][l32 * 4 + 2] = cz * ea + cz_o * eb;
    s_ctx[w][l32 * 4 + 3] = cw * ea + cw_o * eb;
  }
  __syncthreads();

  // merge the block's 4 waves, emit one partial {m,l,ctx[128]} per block
  float* part = part_out + (size_t)blk * NPART_;
  if (t < H_) {
    const float m0 = s_m[0], m1 = s_m[1], m2 = s_m[2], m3 = s_m[3];
    const float Mb = fmaxf(fmaxf(m0, m1), fmaxf(m2, m3));
    const float e0 = __expf(m0 - Mb), e1 = __expf(m1 - Mb);
    const float e2 = __expf(m2 - Mb), e3 = __expf(m3 - Mb);
    if (t == 0) {
      part[0] = Mb;
      part[1] = s_l[0] * e0 + s_l[1] * e1 + s_l[2] * e2 + s_l[3] * e3;
    }
    part[2 + t] = s_ctx[0][t] * e0 + s_ctx[1][t] * e1 +
                  s_ctx[2][t] * e2 + s_ctx[3][t] * e3;
  }

  // coalesced raw-score write-out for this block's 256 positions
  float* so = score_out + (size_t)b * S_ + (size_t)split * CHUNK_;
  if (t < CHUNK_) so[t] = s_score[t];
}

// ---------------- Pass 2: merge split partials, write context, normalize attn -
__global__ __launch_bounds__(256) void s2s_attn_pass2(
    float* __restrict__ attn, float* __restrict__ ctx_out,
    const float* __restrict__ part_in) {
  const int b = blockIdx.x;
  const int t = threadIdx.x;
  const float* base = part_in + (size_t)b * SPLITS_ * NPART_;

  float mv[SPLITS_], lv[SPLITS_], ex[SPLITS_];
  float M = -INFINITY;
#pragma unroll
  for (int p = 0; p < SPLITS_; ++p) {
    mv[p] = base[p * NPART_];
    lv[p] = base[p * NPART_ + 1];
    M = fmaxf(M, mv[p]);
  }
  float L = 0.f;
#pragma unroll
  for (int p = 0; p < SPLITS_; ++p) {
    ex[p] = __expf(mv[p] - M);
    L += lv[p] * ex[p];
  }
  const float invL = 1.0f / L;

  if (t < H_) {
    float c = 0.f;
#pragma unroll
    for (int p = 0; p < SPLITS_; ++p) c += base[p * NPART_ + 2 + t] * ex[p];
    ctx_out[(size_t)b * H_ + t] = c * invL;
  }

  float* ab = attn + (size_t)b * S_;
#pragma unroll 4
  for (int j = t; j < S_; j += 256) ab[j] = __expf(ab[j] - M) * invL;
}

extern "C" void kernel_launch(void* const* d_in, const int* in_sizes, int n_in,
                              void* d_out, int out_size, void* d_ws, size_t ws_size,
                              hipStream_t stream) {
  const float* dec = (const float*)d_in[0];   // (128,128) fp32
  const float* enc = (const float*)d_in[1];   // (128,4096,128) fp32
  float* out = (float*)d_out;
  float* attn = out;                          // (128,4096) — scores, then probs
  float* ctx = out + (size_t)B_ * S_;         // (128,128)
  float* part = (float*)d_ws;                 // 2048 * 130 floats = 1.04 MiB

  s2s_attn_pass1<<<dim3(B_ * SPLITS_), dim3(256), 0, stream>>>(dec, enc, attn, part);
  s2s_attn_pass2<<<dim3(B_), dim3(256), 0, stream>>>(attn, ctx, part);
}